// Round 7
// baseline (266.258 us; speedup 1.0000x reference)
//
#include <hip/hip_runtime.h>

#define EPS_F 1e-5f
#define SCALE_F 0.02f

using short8  = __attribute__((ext_vector_type(8))) short;
using floatx4 = __attribute__((ext_vector_type(4))) float;

__device__ __forceinline__ unsigned short f2bf(float f) {
  unsigned u = __float_as_uint(f);
  return (unsigned short)((u + 0x7fffu + ((u >> 16) & 1u)) >> 16);
}

// ---------------- single prep kernel ----------------
// blocks [0,576): weight pack (gather form; bid>=288 -> w2); bid==0 also does BN.
// blocks [576,2368): x NCHW fp32 -> padded NHWC bf16 + border zeroing (both bufs).
__global__ void prep_all(const float* __restrict__ x,
                         unsigned short* __restrict__ xb, unsigned short* __restrict__ abuf,
                         const float* __restrict__ w1, const float* __restrict__ w2,
                         unsigned short* __restrict__ ap1, unsigned short* __restrict__ ap2,
                         const float* g1, const float* b1, const float* m1, const float* v1,
                         const float* g2, const float* b2, const float* m2, const float* v2,
                         float* bnp) {
  int bid = blockIdx.x;
  int tid = threadIdx.x;
  if (bid < 576) {
    const float* __restrict__ w = (bid >= 288) ? w2 : w1;
    unsigned short* __restrict__ ap = (bid >= 288) ? ap2 : ap1;
    int t = (bid >= 288 ? bid - 288 : bid) * 256 + tid;   // 73728 groups per tensor
    int off = t >> 13;
    int c8  = (t >> 8) & 31;
    int co  = t & 255;
    const float* wsrc = w + (size_t)(co * 256 + c8 * 8) * 9 + off;
    short8 o;
#pragma unroll
    for (int j = 0; j < 8; ++j) {
      float v = wsrc[j * 9];
      o[j] = (v > 0.f) ? (short)0x3F80 : ((v < 0.f) ? (short)0xBF80 : (short)0);
    }
    *(short8*)(ap + (size_t)t * 8) = o;
    if (bid == 0) {
      int c = tid;
      float i1 = g1[c] * rsqrtf(v1[c] + EPS_F);
      bnp[c]       = SCALE_F * i1;
      bnp[256 + c] = b1[c] - m1[c] * i1;
      float i2 = g2[c] * rsqrtf(v2[c] + EPS_F);
      bnp[512 + c] = SCALE_F * i2;
      bnp[768 + c] = b2[c] - m2[c] * i2;
    }
    return;
  }
  // ---- x convert: thread = ci; coalesced NHWC writes ----
  int bid2 = bid - 576;          // 0..1791
  int n = bid2 / 28;
  int h = bid2 - n * 28;
  const float* xs = x + ((size_t)n * 256 + tid) * 784 + h * 28;
  unsigned short* xd = xb + ((size_t)n * 900 + (h + 1) * 30 + 1) * 256 + tid;
#pragma unroll
  for (int p4 = 0; p4 < 7; ++p4) {
    floatx4 f = *(const floatx4*)(xs + p4 * 4);
#pragma unroll
    for (int k = 0; k < 4; ++k)
      xd[(size_t)(p4 * 4 + k) * 256] = f2bf(f[k]);
  }
  // side borders of padded row h+1, both buffers
  {
    int bufi = tid >> 7, side = (tid >> 6) & 1, c4 = tid & 63;
    unsigned short* bb = (bufi ? abuf : xb) + ((size_t)n * 900 + (h + 1) * 30 + side * 29) * 256;
    ushort4 z = {0, 0, 0, 0};
    *(ushort4*)(bb + c4 * 4) = z;
  }
  // top/bottom padded rows
  if (h == 0 || h == 27) {
    int row = (h == 0) ? 0 : 29;
    for (int u = tid; u < 3840; u += 256) {    // 2 bufs * 30px * 64 c4
      int bufi = u / 1920;
      int r    = u - bufi * 1920;
      int px   = r >> 6, c4 = r & 63;
      unsigned short* bb = (bufi ? abuf : xb) + ((size_t)n * 900 + row * 30 + px) * 256;
      ushort4 z = {0, 0, 0, 0};
      *(ushort4*)(bb + c4 * 4) = z;
    }
  }
}

// ---------------- conv (implicit GEMM, halo-tiled, 2-image blocks) ------------
// Block: 256 thr = 4 waves. Macro-tile: 128 co x 224 sp (4 rows x 2 images).
// Wave wv: co [coB*128 + wv*32, +32), all 224 sp -> acc 2x14 floatx4 (112).
// A-loads halved vs 64co x 112sp tile: 2 per half-step, MFMA:A = 14:1.
// LDS: 2 x (6 rows x 30 px) x 64 ci, XOR-swizzled pitch-64; kw unrolled.
template<int STAGE>
__global__ __launch_bounds__(256, 2) void bconv(
    const unsigned short* __restrict__ Bin,
    const unsigned short* __restrict__ Apack,
    const float* __restrict__ bnp,
    unsigned short* __restrict__ aout,
    const float* __restrict__ xres,
    float* __restrict__ out)
{
  __shared__ __align__(16) unsigned short smem[23040];  // 360 px x 64 ci (46080 B)
  unsigned short* Blds = smem;

  const int tid  = threadIdx.x;
  const int lane = tid & 63;
  const int wv   = tid >> 6;
  const int quad = lane >> 4;
  const int l16  = lane & 15;
  const int spBlk = blockIdx.x;        // 0..6
  const int n0    = blockIdx.y * 2;    // image pair
  const int coB   = blockIdx.z;        // 0..1
  const int coBase = coB * 128;

  const int prow0 = 4 * spBlk;
  const unsigned short* bsrc = Bin + ((size_t)n0 * 900 + prow0 * 30) * 256;
  const int coW = coBase + wv * 32;

  int pxS[14];
#pragma unroll
  for (int s = 0; s < 14; ++s) {
    int lm  = s * 16 + l16;            // 0..223
    int img = lm >= 112;
    int lmL = lm - 112 * img;
    int hl  = lmL / 28;
    int w   = lmL - hl * 28;
    pxS[s] = img * 180 + hl * 30 + w;
  }

  floatx4 acc[2][14];
#pragma unroll
  for (int c = 0; c < 2; ++c)
#pragma unroll
    for (int s = 0; s < 14; ++s)
      acc[c][s] = (floatx4){0.f, 0.f, 0.f, 0.f};

#pragma unroll 1
  for (int cb = 0; cb < 4; ++cb) {
    __syncthreads();   // previous ci-block's frag reads complete
    // stage 2 x 180 px x 64 ci (2880 x 16B units), swizzled
    for (int u = tid; u < 2880; u += 256) {
      int px = u >> 3, c = u & 7;
      int imgo = (px >= 180) ? (230400 - 180 * 256) : 0;  // n0+1 image base adj
      const unsigned short* src = bsrc + imgo + (size_t)px * 256 + cb * 64 + c * 8;
      *(short8*)&Blds[(px << 6) + ((c ^ (px & 7)) << 3)] = *(const short8*)src;
    }
    __syncthreads();

    const int cq = cb * 8 + quad;
#pragma unroll 1
    for (int kh = 0; kh < 3; ++kh) {
#pragma unroll
      for (int kw = 0; kw < 3; ++kw) {
        const int D = kh * 30 + kw;
        const int chunk0 = (kh * 3 + kw) * 32 + cq;
#pragma unroll
        for (int half = 0; half < 2; ++half) {
          const int chunk = chunk0 + half * 4;
          const unsigned short* apb = Apack + ((size_t)(chunk * 256 + coW + l16)) * 8;
          short8 a0 = *(const short8*)(apb);
          short8 a1 = *(const short8*)(apb + 16 * 8);
          const int C = half * 4 + quad;
#pragma unroll
          for (int s = 0; s < 14; ++s) {
            int pe = pxS[s] + D;
            short8 b = *(const short8*)&Blds[(pe << 6) + ((C ^ (pe & 7)) << 3)];
            acc[0][s] = __builtin_amdgcn_mfma_f32_16x16x32_bf16(a0, b, acc[0][s], 0, 0, 0);
            acc[1][s] = __builtin_amdgcn_mfma_f32_16x16x32_bf16(a1, b, acc[1][s], 0, 0, 0);
          }
        }
      }
    }
  }

  // Epilogue. C/D layout: col(sp)=l16, row(co within 16-tile)=quad*4+reg.
  if (STAGE == 1) {
    // Per image: BN+ReLU -> LDS[px][coL] (pitch 132), then coalesced copies.
    __syncthreads();   // last cb's Blds reads done before overwrite
#pragma unroll
    for (int p = 0; p < 2; ++p) {
#pragma unroll
      for (int c = 0; c < 2; ++c) {
        int co = coW + c * 16 + quad * 4;
        floatx4 As = *(const floatx4*)(bnp + co);
        floatx4 Bs = *(const floatx4*)(bnp + 256 + co);
        int coL = co - coBase;
#pragma unroll
        for (int si = 0; si < 7; ++si) {
          int s  = p * 7 + si;
          int px = s * 16 + l16 - 112 * p;   // 0..111
          ushort4 o;
          o.x = f2bf(fmaxf(acc[c][s][0] * As[0] + Bs[0], 0.f));
          o.y = f2bf(fmaxf(acc[c][s][1] * As[1] + Bs[1], 0.f));
          o.z = f2bf(fmaxf(acc[c][s][2] * As[2] + Bs[2], 0.f));
          o.w = f2bf(fmaxf(acc[c][s][3] * As[3] + Bs[3], 0.f));
          *(ushort4*)&smem[px * 132 + coL] = o;
        }
      }
      __syncthreads();
      unsigned short* dst0 = aout + ((size_t)(n0 + p) * 900 + (prow0 + 1) * 30 + 1) * 256 + coBase;
      for (int u = tid; u < 1792; u += 256) {   // 112 px * 16 groups of 8 co
        int px = u >> 4;
        int c8 = (u & 15) * 8;
        int r  = px / 28;
        int w  = px - r * 28;
        *(short8*)(dst0 + (size_t)(r * 30 + w) * 256 + c8) = *(const short8*)&smem[px * 132 + c8];
      }
      __syncthreads();
    }
  } else {
#pragma unroll
    for (int c = 0; c < 2; ++c) {
      int co = coW + c * 16 + quad * 4;
      floatx4 As = *(const floatx4*)(bnp + 512 + co);
      floatx4 Bs = *(const floatx4*)(bnp + 768 + co);
#pragma unroll
      for (int s = 0; s < 14; ++s) {
        int lm  = s * 16 + l16;
        int img = lm >= 112;
        int lmL = lm - 112 * img;
        int m   = spBlk * 112 + lmL;
#pragma unroll
        for (int r = 0; r < 4; ++r) {
          size_t oidx = ((size_t)(n0 + img) * 256 + co + r) * 784 + m;
          float v = acc[c][s][r] * As[r] + Bs[r] + xres[oidx];
          out[oidx] = fmaxf(v, 0.f);
        }
      }
    }
  }
}

// ---------------- launch ----------------

extern "C" void kernel_launch(void* const* d_in, const int* in_sizes, int n_in,
                              void* d_out, int out_size, void* d_ws, size_t ws_size,
                              hipStream_t stream) {
  const float* x  = (const float*)d_in[0];
  const float* w1 = (const float*)d_in[1];
  const float* g1 = (const float*)d_in[2];
  const float* b1 = (const float*)d_in[3];
  const float* m1 = (const float*)d_in[4];
  const float* v1 = (const float*)d_in[5];
  const float* w2 = (const float*)d_in[6];
  const float* g2 = (const float*)d_in[7];
  const float* b2 = (const float*)d_in[8];
  const float* m2 = (const float*)d_in[9];
  const float* v2 = (const float*)d_in[10];
  float* out = (float*)d_out;

  char* ws = (char*)d_ws;
  const size_t PADBUF = (size_t)64 * 900 * 256 * 2;   // 29,491,200 B
  const size_t WPACK  = 589824ull * 2;                 // 1,179,648 B
  unsigned short* xb   = (unsigned short*)ws;
  unsigned short* abuf = (unsigned short*)(ws + PADBUF);
  unsigned short* ap1  = (unsigned short*)(ws + 2 * PADBUF);
  unsigned short* ap2  = (unsigned short*)(ws + 2 * PADBUF + WPACK);
  float* bnp           = (float*)(ws + 2 * PADBUF + 2 * WPACK);

  prep_all<<<2368, 256, 0, stream>>>(x, xb, abuf, w1, w2, ap1, ap2,
                                     g1, b1, m1, v1, g2, b2, m2, v2, bnp);

  dim3 grid(7, 32, 2);   // sp-tile, image-pair, co-half
  bconv<1><<<grid, 256, 0, stream>>>(xb,   ap1, bnp, abuf, nullptr, nullptr);
  bconv<2><<<grid, 256, 0, stream>>>(abuf, ap2, bnp, nullptr, x, out);
}